// Round 1
// baseline (29.412 us; speedup 1.0000x reference)
//
#include <hip/hip_runtime.h>
#include <math.h>

// EdgeConstructor: out[b][i][j] = { dR(i,j), mass(i,j) } for B=256, N=256.
// Memory-bound on the 134 MB f32 output. Per-node trig hoisted to LDS.

#define BATCH 256
#define NN 256
#define TI 16  // rows per block

__global__ __launch_bounds__(256)
void edge_kernel(const float* __restrict__ x, float* __restrict__ out) {
    const int b   = blockIdx.y;
    const int i0  = blockIdx.x * TI;
    const int tid = threadIdx.x;

    __shared__ float s_eta[NN], s_phi[NN], s_E[NN];
    __shared__ float s_px[NN], s_py[NN], s_pz[NN];

    // Phase 1: each thread precomputes node `tid` of batch b.
    const float4 v = reinterpret_cast<const float4*>(x)[b * NN + tid];
    const float pt  = v.x;
    const float eta = v.y;
    const float phi = v.z;
    const float E   = v.w;
    float sp, cp;
    sincosf(phi, &sp, &cp);
    const float px = pt * cp;
    const float py = pt * sp;
    const float pz = pt * sinhf(eta);

    s_eta[tid] = eta; s_phi[tid] = phi; s_E[tid] = E;
    s_px[tid]  = px;  s_py[tid]  = py;  s_pz[tid] = pz;
    __syncthreads();

    const float PI         = 3.14159265358979323846f;
    const float TWO_PI     = 6.28318530717958647692f;
    const float INV_TWO_PI = 0.15915494309189533577f;

    // Phase 2: thread = column j = tid; loop over TI rows.
    float2* outp = reinterpret_cast<float2*>(out)
                 + ((size_t)b * NN + (size_t)i0) * NN + tid;

#pragma unroll
    for (int r = 0; r < TI; ++r) {
        const int i = i0 + r;
        // row-i values: LDS broadcast (uniform address across lanes)
        const float eta_i = s_eta[i];
        const float phi_i = s_phi[i];
        const float E_i   = s_E[i];
        const float px_i  = s_px[i];
        const float py_i  = s_py[i];
        const float pz_i  = s_pz[i];

        const float deta = eta_i - eta;
        float t = (phi_i - phi) + PI;
        t -= TWO_PI * floorf(t * INV_TWO_PI);   // jnp.mod(dphi+pi, 2pi)
        const float dphi = t - PI;
        const float dR = sqrtf(fmaxf(fmaf(deta, deta, dphi * dphi), 1e-12f));

        const float es  = E_i  + E;
        const float pxs = px_i + px;
        const float pys = py_i + py;
        const float pzs = pz_i + pz;
        const float m2 = es * es - pxs * pxs - pys * pys - pzs * pzs;
        const float mass = sqrtf(fmaxf(m2, 1e-12f));

        outp[(size_t)r * NN] = make_float2(dR, mass);
    }
}

extern "C" void kernel_launch(void* const* d_in, const int* in_sizes, int n_in,
                              void* d_out, int out_size, void* d_ws, size_t ws_size,
                              hipStream_t stream) {
    const float* x = (const float*)d_in[0];
    float* out = (float*)d_out;
    dim3 grid(NN / TI, BATCH);
    dim3 block(256);
    edge_kernel<<<grid, block, 0, stream>>>(x, out);
}